// Round 12
// baseline (733.282 us; speedup 1.0000x reference)
//
#include <hip/hip_runtime.h>

#define D 256
#define B 128
#define S 64
#define L 32
#define K 32
#define KH 16
#define NW 8      // waves per recur block (512 threads), 32 cols/wave
#define NSUB 2    // 2 adjacent cols per lane (col2 remap)
#define HSTR 260  // u16 stride (proven 0-conflict R7/R8)

typedef _Float16 f16x8 __attribute__((ext_vector_type(8)));  // 8 f16 in 4 VGPRs
typedef float f32x4 __attribute__((ext_vector_type(4)));
typedef unsigned short u16;
typedef unsigned int u32;

__device__ __forceinline__ u16 h_bits(_Float16 h) {
    union { _Float16 h; u16 u; } x; x.h = h; return x.u;
}
// 8 contiguous floats -> f16 hi/lo fragments
__device__ __forceinline__ void cvt8(const float* p, f16x8& hi, f16x8& lo) {
    const float4 a = *(const float4*)p;
    const float4 b = *(const float4*)(p + 4);
    #pragma unroll
    for (int j = 0; j < 8; ++j) {
        const float v = (j < 4) ? ((const float*)&a)[j] : ((const float*)&b)[j - 4];
        const _Float16 vh = (_Float16)v;
        hi[j] = vh;
        lo[j] = (_Float16)(v - (float)vh);
    }
}
// 8 stride-D floats (weight column) -> f16 hi/lo fragments
__device__ __forceinline__ void cvt8s(const float* p, f16x8& hi, f16x8& lo) {
    #pragma unroll
    for (int j = 0; j < 8; ++j) {
        const float v = p[(size_t)j * D];
        const _Float16 vh = (_Float16)v;
        hi[j] = vh;
        lo[j] = (_Float16)(v - (float)vh);
    }
}

// ---------------------------------------------------------------------------
// R21 pre_kernel: gather + MFMA GEMMs FUSED so the GEMMs overlap the
// gather's BW-bound phase across co-resident blocks (12 waves/CU, 3 blocks).
// R11 showed the non-loop cost is conserved (~127µs) when gather and GEMMs
// are stream-serialized; this merges them.
// Blocks [0,512): 16 sentences each —
//   scan+mask -> gather own rows -> write enc (ONCE; no XCD write storm,
//   R9 lesson) -> __syncthreads (own-XCD L2-hot) -> A-frags HELD (one enc
//   read serves eW AND ek; R11 read enc twice) -> eW (4 col-subtiles,
//   streamed W cvt8s) -> ek (waves 0,1; streamed keys cvt8).
// Blocks [512,768): keysV = keys @ V, same held-A/streamed-B pattern.
// All MFMA paths are the R9/R10/R11-verified f16 hi/lo 3-product (absmax
// 1.95e-3 across three rounds). Outputs stored f32 (better than R11's f16).
// Unmasked enc rows are stale ws garbage -> flows only into eW/ek ROWS
// never visited by the loop (MFMA rows don't cross-contaminate). Benign.
// ---------------------------------------------------------------------------
__global__ __launch_bounds__(256) void pre_kernel(
    const int* __restrict__ prgrph, const float* __restrict__ E,
    const float* __restrict__ Wm, const float* __restrict__ Vm,
    const float* __restrict__ keys, const void* __restrict__ mraw,
    float* __restrict__ enc, float* __restrict__ eW,
    float* __restrict__ keysV, float* __restrict__ ek,
    int* __restrict__ mask_out) {
    const int t = threadIdx.x, wave = t >> 6, lane = t & 63;
    const int n = lane & 15, quad = lane >> 4;

    if (blockIdx.x < (B * S) / 16) {
        // ================= eW/ek block: 16 sentences =================
        const int bid = blockIdx.x;
        const int b = bid >> 2;               // 4 blocks per batch entry
        __shared__ int flag;
        __shared__ int smask[16];
        __shared__ int sidx[16][L];           // 2 KB
        if (t == 0) flag = 0;
        __syncthreads();
        {   // format detect: same 1024-word scan semantics as ever
            const u32* w32 = (const u32*)mraw;
            int loc = 0;
            #pragma unroll
            for (int j = 0; j < 4; ++j)
                if (w32[t * 4 + j] > 1u) loc = 1;
            if (loc) flag = 1;   // benign race
        }
        #pragma unroll
        for (int j = 0; j < 2; ++j) {
            const int idx = t * 2 + j;
            sidx[idx >> 5][idx & 31] = prgrph[(size_t)bid * (16 * L) + idx];
        }
        __syncthreads();
        if (t < 16) {
            const int gi = bid * 16 + t;
            const int mv = (flag != 0)
                ? (int)((const unsigned char*)mraw)[(size_t)gi * L]
                : ((const int*)mraw)[(size_t)gi * L];
            smask[t] = mv;
            mask_out[gi] = mv;
        }
        __syncthreads();

        // ---- gather: wave owns 4 sentences; enc written ONCE ----
        {
            const float4* E4 = (const float4*)E;
            for (int sl = wave * 4; sl < wave * 4 + 4; ++sl) {
                if (!smask[sl]) continue;
                float4 a = make_float4(0.f, 0.f, 0.f, 0.f);
                #pragma unroll
                for (int l = 0; l < L; ++l) {
                    const float4 v = E4[(size_t)sidx[sl][l] * (D / 4) + lane];
                    a.x += v.x; a.y += v.y; a.z += v.z; a.w += v.w;
                }
                *(float4*)&enc[(size_t)(bid * 16 + sl) * D + lane * 4] = a;
            }
        }
        __syncthreads();   // drains vmcnt -> own-XCD L2 serves the re-reads

        // ---- A-frags HELD: row = local sentence n (L2-hot re-read) ----
        f16x8 ah[8], al[8];
        #pragma unroll
        for (int kt = 0; kt < 8; ++kt)
            cvt8(enc + (size_t)(bid * 16 + n) * D + kt * 32 + quad * 8,
                 ah[kt], al[kt]);

        // ---- eW: 4 col-subtiles/wave (wave*64+sub*16+n), streamed W ----
        #pragma unroll
        for (int sub = 0; sub < 4; ++sub) {
            const int col = wave * 64 + sub * 16 + n;
            f32x4 acc = (f32x4){0.f, 0.f, 0.f, 0.f};
            for (int kt = 0; kt < 8; ++kt) {
                f16x8 bh, bl;
                cvt8s(Wm + (size_t)(kt * 32 + quad * 8) * D + col, bh, bl);
                acc = __builtin_amdgcn_mfma_f32_16x16x32_f16(ah[kt], bh, acc, 0, 0, 0);
                acc = __builtin_amdgcn_mfma_f32_16x16x32_f16(ah[kt], bl, acc, 0, 0, 0);
                acc = __builtin_amdgcn_mfma_f32_16x16x32_f16(al[kt], bh, acc, 0, 0, 0);
            }
            #pragma unroll
            for (int reg = 0; reg < 4; ++reg)
                eW[(size_t)(bid * 16 + quad * 4 + reg) * D + col] = acc[reg];
        }

        // ---- ek: waves 0,1 (sub = wave), reusing the HELD A-frags ----
        if (wave < 2) {
            const int ent = wave * 16 + n;    // entity 0..31
            f32x4 acc = (f32x4){0.f, 0.f, 0.f, 0.f};
            for (int kt = 0; kt < 8; ++kt) {
                f16x8 kh, kl;
                cvt8(keys + (size_t)(b * K + ent) * D + kt * 32 + quad * 8, kh, kl);
                acc = __builtin_amdgcn_mfma_f32_16x16x32_f16(ah[kt], kh, acc, 0, 0, 0);
                acc = __builtin_amdgcn_mfma_f32_16x16x32_f16(ah[kt], kl, acc, 0, 0, 0);
                acc = __builtin_amdgcn_mfma_f32_16x16x32_f16(al[kt], kh, acc, 0, 0, 0);
            }
            #pragma unroll
            for (int reg = 0; reg < 4; ++reg)
                ek[(size_t)(bid * 16 + quad * 4 + reg) * K + ent] = acc[reg];
        }
    } else {
        // ================= keysV block: 16 key rows =================
        const int idx = blockIdx.x - (B * S) / 16;   // [0,256)
        f16x8 ah[8], al[8];
        #pragma unroll
        for (int kt = 0; kt < 8; ++kt)
            cvt8(keys + (size_t)(idx * 16 + n) * D + kt * 32 + quad * 8,
                 ah[kt], al[kt]);
        #pragma unroll
        for (int sub = 0; sub < 4; ++sub) {
            const int col = wave * 64 + sub * 16 + n;
            f32x4 acc = (f32x4){0.f, 0.f, 0.f, 0.f};
            for (int kt = 0; kt < 8; ++kt) {
                f16x8 bh, bl;
                cvt8s(Vm + (size_t)(kt * 32 + quad * 8) * D + col, bh, bl);
                acc = __builtin_amdgcn_mfma_f32_16x16x32_f16(ah[kt], bh, acc, 0, 0, 0);
                acc = __builtin_amdgcn_mfma_f32_16x16x32_f16(ah[kt], bl, acc, 0, 0, 0);
                acc = __builtin_amdgcn_mfma_f32_16x16x32_f16(al[kt], bh, acc, 0, 0, 0);
            }
            #pragma unroll
            for (int reg = 0; reg < 4; ++reg)
                keysV[(size_t)(idx * 16 + quad * 4 + reg) * D + col] = acc[reg];
        }
    }
}

// ---------------------------------------------------------------------------
// Recurrence: EXACT R5/R7-proven 91µs kernel (reads eWp/keysV/ek/enc from
// global). Block = (b, 16-row half of K); 512 threads = 8 waves.
// R14 col remap (col2 = wave*32+2n), packed b32 h-writes, value-splitting
// butterfly (8 shuffles). R10-R12: KEEP __syncthreads; setprio negative.
// NOTE: 128 VGPR + 128 pinned AGPR = 256 regs/wave -> 1 block/CU, 512
// blocks = 2 occupancy rounds (corrected accounting; earlier "2 blocks/CU"
// comments were wrong — cooperative launch is NOT possible at this grid).
// ek is indexed by ABSOLUTE entity -> kh offset required (R3 bug).
// ---------------------------------------------------------------------------
__global__ __launch_bounds__(512, 2) void recur_kernel(
    const float* __restrict__ enc, const float* __restrict__ eWp,
    const float* __restrict__ keysV, const float* __restrict__ ek,
    const float* __restrict__ U, const int* __restrict__ mask,
    float* __restrict__ out) {
    const int b  = blockIdx.x >> 1;
    const int kh = (blockIdx.x & 1) * KH;
    const int t = threadIdx.x;
    const int wave = t >> 6, lane = t & 63;
    const int n = lane & 15, quad = lane >> 4;
    const int col2 = wave * 32 + 2 * n;      // base of this lane's col pair

    __shared__ u16 hF[2][KH][HSTR];      // 2 x 8.1 KB, f16 h planes
    __shared__ float redN[2][KH][NW];
    __shared__ float redG[2][KH][NW];

    // ---- preload U B-fragments (f16 hi/lo): 128 AGPRs, pinned ----
    f16x8 Uhi[NSUB][8], Ulo[NSUB][8];
    #pragma unroll
    for (int sub = 0; sub < NSUB; ++sub) {
        const int col = col2 + sub;
        #pragma unroll
        for (int kt = 0; kt < 8; ++kt) {
            #pragma unroll
            for (int j = 0; j < 8; ++j) {
                const int k = kt * 32 + quad * 8 + j;
                const float u = U[(size_t)k * D + col];
                const _Float16 uh = (_Float16)u;
                Uhi[sub][kt][j] = uh;
                Ulo[sub][kt][j] = (_Float16)(u - (float)uh);
            }
        }
    }
    #pragma unroll
    for (int sub = 0; sub < NSUB; ++sub)
        #pragma unroll
        for (int kt = 0; kt < 8; ++kt)
            asm volatile("" : "+a"(Uhi[sub][kt]), "+a"(Ulo[sub][kt]));

    // ---- per-lane state ----
    float upv[4][NSUB];
    float rn[4];
    float keysVc[4][NSUB];
    #pragma unroll
    for (int reg = 0; reg < 4; ++reg) {
        rn[reg] = 1.f;
        const size_t base = (size_t)(b * K + kh + quad * 4 + reg) * D;
        const float2 kv2 = *(const float2*)&keysV[base + col2];
        keysVc[reg][0] = kv2.x; keysVc[reg][1] = kv2.y;
        upv[reg][0] = 0.f; upv[reg][1] = 0.f;
    }

    const int* bm = mask + b * S;
    unsigned long long rem = __ballot(bm[lane] != 0);

    float eWc[NSUB];
    float4 ekv = make_float4(0.f, 0.f, 0.f, 0.f);
    eWc[0] = 0.f; eWc[1] = 0.f;
    if (rem) {
        const int s0 = (int)__builtin_ctzll(rem);
        const float2 w2 = *(const float2*)&eWp[(size_t)(b * S + s0) * D + col2];
        eWc[0] = w2.x; eWc[1] = w2.y;
        ekv = *(const float4*)(ek + (size_t)(b * S + s0) * K + kh + quad * 4);
    }

    int p = 0, q = 0;
    bool first = true;
    while (rem) {
        rem &= rem - 1;
        const int sn = rem ? (int)__builtin_ctzll(rem) : -1;

        // ---- issue next-step e load early (covered by MFMA) ----
        float e_n[NSUB];
        e_n[0] = 0.f; e_n[1] = 0.f;
        if (sn >= 0) {
            const float2 e2 = *(const float2*)&enc[(size_t)(b * S + sn) * D + col2];
            e_n[0] = e2.x; e_n[1] = e2.y;
        }

        // ---- MFMA: acc = h_prev @ (Uhi,Ulo), 4 indep chains of 8 ----
        f32x4 acc[NSUB][2];
        #pragma unroll
        for (int sub = 0; sub < NSUB; ++sub) {
            acc[sub][0] = (f32x4){0.f, 0.f, 0.f, 0.f};
            acc[sub][1] = (f32x4){0.f, 0.f, 0.f, 0.f};
        }
        if (!first) {
            #pragma unroll
            for (int kt = 0; kt < 8; ++kt) {
                const f16x8 av = *(const f16x8*)&hF[p][n][kt * 32 + quad * 8];
                #pragma unroll
                for (int sub = 0; sub < NSUB; ++sub) {
                    acc[sub][0] = __builtin_amdgcn_mfma_f32_16x16x32_f16(av, Uhi[sub][kt], acc[sub][0], 0, 0, 0);
                    acc[sub][1] = __builtin_amdgcn_mfma_f32_16x16x32_f16(av, Ulo[sub][kt], acc[sub][1], 0, 0, 0);
                }
            }
        }

        // ---- gate ----
        float gate[4];
        #pragma unroll
        for (int reg = 0; reg < 4; ++reg) {
            const float ekb = (reg == 0) ? ekv.x : (reg == 1) ? ekv.y
                            : (reg == 2) ? ekv.z : ekv.w;
            float g = ekb;
            if (!first) {
                const float* rg = redG[q ^ 1][quad * 4 + reg];
                const float4 g0 = *(const float4*)rg;
                const float4 g1 = *(const float4*)(rg + 4);
                g += rn[reg] * (g0.x + g0.y + g0.z + g0.w +
                                g1.x + g1.y + g1.z + g1.w);
            }
            gate[reg] = 1.f / (1.f + __expf(-g));
        }

        // ---- update + packed f16 h write + norm/gate-dot partials ----
        const int pw = p ^ 1;
        float pn[4], gd[4];
        #pragma unroll
        for (int reg = 0; reg < 4; ++reg) {
            const int row = quad * 4 + reg;
            float sq = 0.f, dv = 0.f;
            float u2s[2];
            #pragma unroll
            for (int sub = 0; sub < NSUB; ++sub) {
                const float asum = acc[sub][0][reg] + acc[sub][1][reg];
                float ht = rn[reg] * asum + keysVc[reg][sub] + eWc[sub];
                ht = fmaxf(ht, 0.f);
                const float u2 = rn[reg] * upv[reg][sub] + gate[reg] * ht;
                upv[reg][sub] = u2;
                u2s[sub] = u2;
                sq += u2 * u2;
                dv += u2 * e_n[sub];
            }
            const u32 packed =
                ((u32)h_bits((_Float16)u2s[1]) << 16) |
                (u32)h_bits((_Float16)u2s[0]);
            *(u32*)&hF[pw][row][col2] = packed;
            pn[reg] = sq;
            gd[reg] = dv;
        }

        // ---- reload step-invariants IN PLACE (last use passed) ----
        if (sn >= 0) {
            const float2 w2 = *(const float2*)&eWp[(size_t)(b * S + sn) * D + col2];
            eWc[0] = w2.x; eWc[1] = w2.y;
            ekv = *(const float4*)(ek + (size_t)(b * S + sn) * K + kh + quad * 4);
        }

        // ---- value-splitting butterfly: 8 shuffles (R14-proven) ----
        {
            float v0 = pn[0], v1 = pn[1], v2 = pn[2], v3 = pn[3];
            float w0 = gd[0], w1 = gd[1], w2 = gd[2], w3 = gd[3];
            {   // xor 1
                const bool hi = (n & 1);
                float k0 = hi ? w0 : v0, x0 = hi ? v0 : w0;
                float k1 = hi ? w1 : v1, x1 = hi ? v1 : w1;
                float k2 = hi ? w2 : v2, x2 = hi ? v2 : w2;
                float k3 = hi ? w3 : v3, x3 = hi ? v3 : w3;
                v0 = k0 + __shfl_xor(x0, 1);
                v1 = k1 + __shfl_xor(x1, 1);
                v2 = k2 + __shfl_xor(x2, 1);
                v3 = k3 + __shfl_xor(x3, 1);
            }
            {   // xor 2
                const bool hi = (n & 2);
                float k0 = hi ? v2 : v0, x0 = hi ? v0 : v2;
                float k1 = hi ? v3 : v1, x1 = hi ? v1 : v3;
                v0 = k0 + __shfl_xor(x0, 2);
                v1 = k1 + __shfl_xor(x1, 2);
            }
            {   // xor 4
                const bool hi = (n & 4);
                float k0 = hi ? v1 : v0, x0 = hi ? v0 : v1;
                v0 = k0 + __shfl_xor(x0, 4);
            }
            v0 += __shfl_xor(v0, 8);
            if (n < 8) {
                const int vid = ((n & 1) << 2) | (n & 2) | ((n >> 2) & 1);
                const int row = quad * 4 + (vid & 3);
                float* dst = (vid & 4) ? &redG[q][row][wave]
                                       : &redN[q][row][wave];
                *dst = v0;
            }
        }

        __syncthreads();   // the ONLY loop barrier (R12-proven form)

        #pragma unroll
        for (int reg = 0; reg < 4; ++reg) {
            const float* rp = redN[q][quad * 4 + reg];
            const float4 r0 = *(const float4*)rp;
            const float4 r1 = *(const float4*)(rp + 4);
            rn[reg] = rsqrtf(fmaxf(r0.x + r0.y + r0.z + r0.w +
                                   r1.x + r1.y + r1.z + r1.w, 1e-12f));
        }
        p ^= 1; q ^= 1; first = false;
    }

    #pragma unroll
    for (int reg = 0; reg < 4; ++reg) {
        const size_t base = (size_t)(b * K + kh + quad * 4 + reg) * D;
        const float2 o2 = make_float2(rn[reg] * upv[reg][0],
                                      rn[reg] * upv[reg][1]);
        *(float2*)&out[base + col2] = o2;
    }
}

extern "C" void kernel_launch(void* const* d_in, const int* in_sizes, int n_in,
                              void* d_out, int out_size, void* d_ws, size_t ws_size,
                              hipStream_t stream) {
    const int*   prgrph = (const int*)d_in[0];
    const void*  pmask  = d_in[1];
    const float* keys   = (const float*)d_in[2];
    const float* E      = (const float*)d_in[3];
    const float* U      = (const float*)d_in[4];
    const float* V      = (const float*)d_in[5];
    const float* W      = (const float*)d_in[6];
    float* out = (float*)d_out;

    float* ws_enc   = (float*)d_ws;                          // B*S*D  (8 MB)
    float* ws_eW    = ws_enc + (size_t)B * S * D;            // B*S*D  (8 MB)
    float* ws_keysV = ws_eW  + (size_t)B * S * D;            // B*K*D  (4 MB)
    float* ws_ek    = ws_keysV + (size_t)B * K * D;          // B*S*K  (1 MB)
    int*   ws_mask  = (int*)(ws_ek + (size_t)B * S * K);     // B*S

    pre_kernel<<<(B * S) / 16 + (B * K) / 16, 256, 0, stream>>>(
        prgrph, E, W, V, keys, pmask, ws_enc, ws_eW, ws_keysV, ws_ek, ws_mask);
    recur_kernel<<<B * (K / KH), 512, 0, stream>>>(
        ws_enc, ws_eW, ws_keysV, ws_ek, U, ws_mask, out);
}

// Round 13
// 215.040 us; speedup vs baseline: 3.4100x; 3.4100x over previous
//
#include <hip/hip_runtime.h>

#define D 256
#define B 128
#define S 64
#define L 32
#define K 32
#define KH 16
#define NW 8      // waves per recurrence block (512 threads), 32 cols/wave
#define NSUB 2    // 16-col sub-tiles per wave
#define HSTR 260  // u16 stride (proven 0-conflict R7/R8)

typedef _Float16 f16x8 __attribute__((ext_vector_type(8)));  // 8 f16 in 4 VGPRs
typedef float f32x4 __attribute__((ext_vector_type(4)));
typedef unsigned short u16;

__device__ __forceinline__ u16 h_bits(_Float16 h) {
    union { _Float16 h; u16 u; } x; x.h = h; return x.u;
}

// ---------------------------------------------------------------------------
// R22 = EXACT revert to the R16/R7 ledger-best (216.9µs measured).
// pre_kernel: 256 threads, 384 blocks; eW blocks own 32 sentences (fused
// mask scan, gather into LDS+global, eW GEMM from LDS, ek from LDS-staged
// keys); keysV blocks plain-GEMM 32 key rows. Every attempted perturbation
// of this shape regressed: R4 regrain -20µs, R6 512-thr -9µs, R8 B-staging
// -15µs, R12/R21 streamed-MFMA-fusion -516µs. The ~85µs cost is gather
// latency/BW + B-stream, structural at this decomposition.
// ---------------------------------------------------------------------------
__global__ __launch_bounds__(256) void pre_kernel(
    const int* __restrict__ prgrph, const float* __restrict__ E,
    const float* __restrict__ Wm, const float* __restrict__ Vm,
    const float* __restrict__ keys, const void* __restrict__ mraw,
    float* __restrict__ enc, float* __restrict__ eW,
    float* __restrict__ keysV, float* __restrict__ ek,
    int* __restrict__ mask_out) {
    const int t = threadIdx.x, wave = t >> 6, lane = t & 63;
    __shared__ int   flag;
    __shared__ int   smask[32];
    __shared__ int   sidx[32][L];        // 4 KB
    __shared__ float a_s[32][264];       // 33.8 KB (padded)
    __shared__ float ks[32][260];        // 33.3 KB (padded)

    const float* Bm;
    float* O;

    if (blockIdx.x < (B * S) / 32) {
        const int bid = blockIdx.x;          // b = bid>>1, half = bid&1

        if (t == 0) flag = 0;
        __syncthreads();
        // format detect: same 1024-word scan semantics as old mask_kernel
        {
            const unsigned int* w32 = (const unsigned int*)mraw;
            int loc = 0;
            #pragma unroll
            for (int j = 0; j < 4; ++j)
                if (w32[t * 4 + j] > 1u) loc = 1;
            if (loc) flag = 1;   // benign race
        }
        #pragma unroll
        for (int j = 0; j < 4; ++j) {
            const int idx = t * 4 + j;
            sidx[idx >> 5][idx & 31] = prgrph[(size_t)bid * 1024 + idx];
        }
        __syncthreads();
        if (t < 32) {
            const int gi = bid * 32 + t;
            const int mv = (flag != 0)
                ? (int)((const unsigned char*)mraw)[(size_t)gi * L]
                : ((const int*)mraw)[(size_t)gi * L];
            smask[t] = mv;
            mask_out[gi] = mv;
        }
        __syncthreads();

        const float4* E4 = (const float4*)E;
        for (int sl = wave * 8; sl < wave * 8 + 8; ++sl) {
            if (!smask[sl]) continue;
            float4 a = make_float4(0.f, 0.f, 0.f, 0.f);
            #pragma unroll
            for (int l = 0; l < L; ++l) {
                const float4 v = E4[(size_t)sidx[sl][l] * (D / 4) + lane];
                a.x += v.x; a.y += v.y; a.z += v.z; a.w += v.w;
            }
            *(float4*)&a_s[sl][lane * 4] = a;
            *(float4*)&enc[(size_t)(bid * 32 + sl) * D + lane * 4] = a;
        }
        __syncthreads();
        Bm = Wm;
        O = eW + (size_t)bid * 32 * D;
    } else {
        const int row0 = (blockIdx.x - (B * S) / 32) * 32;
        const float4* Ag = (const float4*)(keys + (size_t)row0 * D);
        for (int i = t; i < 32 * D / 4; i += 256) {
            const float4 v = Ag[i];
            *(float4*)&a_s[i >> 6][(i & 63) * 4] = v;
        }
        __syncthreads();
        Bm = Vm;
        O = keysV + (size_t)row0 * D;
    }

    // ---- GEMM: 32 rows @ DxD; wave computes rows [wave*8, wave*8+8) ----
    {
        const int r0 = wave * 8, c0 = lane * 4;
        float4 acc[8];
        #pragma unroll
        for (int i = 0; i < 8; ++i) acc[i] = make_float4(0.f, 0.f, 0.f, 0.f);
        for (int d = 0; d < D; d += 4) {
            float4 av[8];
            #pragma unroll
            for (int i = 0; i < 8; ++i) av[i] = *(const float4*)&a_s[r0 + i][d];
            #pragma unroll
            for (int j = 0; j < 4; ++j) {
                const float4 w = *(const float4*)(Bm + (size_t)(d + j) * D + c0);
                #pragma unroll
                for (int i = 0; i < 8; ++i) {
                    const float a = (j == 0) ? av[i].x : (j == 1) ? av[i].y
                                  : (j == 2) ? av[i].z : av[i].w;
                    acc[i].x += a * w.x; acc[i].y += a * w.y;
                    acc[i].z += a * w.z; acc[i].w += a * w.w;
                }
            }
        }
        #pragma unroll
        for (int i = 0; i < 8; ++i)
            *(float4*)&O[(size_t)(r0 + i) * D + c0] = acc[i];
    }

    if (blockIdx.x >= (B * S) / 32) return;

    // ---- ek from LDS-staged keys ----
    {
        const int bid = blockIdx.x;
        const int b = bid >> 1;
        const float4* kg = (const float4*)(keys + (size_t)b * K * D);
        for (int i = t; i < K * D / 4; i += 256) {
            const float4 v = kg[i];
            *(float4*)&ks[i >> 6][(i & 63) * 4] = v;
        }
        __syncthreads();
        const int sl = t >> 3, kq = t & 7;           // k = kq + 8j
        if (smask[sl]) {
            float acc[4];
            #pragma unroll
            for (int j = 0; j < 4; ++j) acc[j] = 0.f;
            for (int d4 = 0; d4 < D / 4; ++d4) {
                const float4 e = *(const float4*)&a_s[sl][d4 * 4];
                #pragma unroll
                for (int j = 0; j < 4; ++j) {
                    const float4 kv = *(const float4*)&ks[kq + 8 * j][d4 * 4];
                    acc[j] += e.x * kv.x + e.y * kv.y + e.z * kv.z + e.w * kv.w;
                }
            }
            #pragma unroll
            for (int j = 0; j < 4; ++j)
                ek[(size_t)(bid * 32 + sl) * K + kq + 8 * j] = acc[j];
        }
    }
}

// ---------------------------------------------------------------------------
// Recurrence (UNCHANGED R5/R7-proven 91µs version).
// Block = (b, 16-row half of K); 512 threads = 8 waves.
// R14 col remap: wave w, lane (n,quad) sub-tile s handles PHYSICAL col
// wave*32 + 2n + sub. Packed b32 h-writes; float2 e/eW/keysV/out accesses.
// R14 reduce: value-splitting butterfly -- 8 shuffles, exec-masked red-write.
// R10-R12 barrier A/B: KEEP __syncthreads(). setprio: negative here.
// ek is indexed by ABSOLUTE entity -> kh offset required (R3 bug).
// ---------------------------------------------------------------------------
__global__ __launch_bounds__(512, 2) void recur_kernel(
    const float* __restrict__ enc, const float* __restrict__ eWp,
    const float* __restrict__ keysV, const float* __restrict__ ek,
    const float* __restrict__ U, const int* __restrict__ mask,
    float* __restrict__ out) {
    const int b  = blockIdx.x >> 1;
    const int kh = (blockIdx.x & 1) * KH;
    const int t = threadIdx.x;
    const int wave = t >> 6, lane = t & 63;
    const int n = lane & 15, quad = lane >> 4;
    const int col2 = wave * 32 + 2 * n;      // base of this lane's col pair

    __shared__ u16 hF[2][KH][HSTR];      // 2 x 8.1 KB, f16 h planes
    __shared__ float redN[2][KH][NW];
    __shared__ float redG[2][KH][NW];

    // ---- preload U B-fragments (f16 hi/lo): 2 subs x 8 kt -> 128 AGPRs ----
    f16x8 Uhi[NSUB][8], Ulo[NSUB][8];
    #pragma unroll
    for (int sub = 0; sub < NSUB; ++sub) {
        const int col = col2 + sub;
        #pragma unroll
        for (int kt = 0; kt < 8; ++kt) {
            #pragma unroll
            for (int j = 0; j < 8; ++j) {
                const int k = kt * 32 + quad * 8 + j;
                const float u = U[(size_t)k * D + col];
                const _Float16 uh = (_Float16)u;
                Uhi[sub][kt][j] = uh;
                Ulo[sub][kt][j] = (_Float16)(u - (float)uh);
            }
        }
    }
    #pragma unroll
    for (int sub = 0; sub < NSUB; ++sub)
        #pragma unroll
        for (int kt = 0; kt < 8; ++kt)
            asm volatile("" : "+a"(Uhi[sub][kt]), "+a"(Ulo[sub][kt]));

    // ---- per-lane state ----
    float upv[4][NSUB];
    float rn[4];
    float keysVc[4][NSUB];
    #pragma unroll
    for (int reg = 0; reg < 4; ++reg) {
        rn[reg] = 1.f;
        const size_t base = (size_t)(b * K + kh + quad * 4 + reg) * D;
        const float2 kv2 = *(const float2*)&keysV[base + col2];
        keysVc[reg][0] = kv2.x; keysVc[reg][1] = kv2.y;
        upv[reg][0] = 0.f; upv[reg][1] = 0.f;
    }

    const int* bm = mask + b * S;
    unsigned long long rem = __ballot(bm[lane & 63] != 0);

    float eWc[NSUB];
    float4 ekv = make_float4(0.f, 0.f, 0.f, 0.f);
    eWc[0] = 0.f; eWc[1] = 0.f;
    if (rem) {
        const int s0 = (int)__builtin_ctzll(rem);
        const float2 w2 = *(const float2*)&eWp[(size_t)(b * S + s0) * D + col2];
        eWc[0] = w2.x; eWc[1] = w2.y;
        ekv = *(const float4*)(ek + (size_t)(b * S + s0) * K + kh + quad * 4);
    }

    int p = 0, q = 0;
    bool first = true;
    while (rem) {
        rem &= rem - 1;
        const int sn = rem ? (int)__builtin_ctzll(rem) : -1;

        // ---- issue next-step e load early (covered by MFMA) ----
        float e_n[NSUB];
        e_n[0] = 0.f; e_n[1] = 0.f;
        if (sn >= 0) {
            const float2 e2 = *(const float2*)&enc[(size_t)(b * S + sn) * D + col2];
            e_n[0] = e2.x; e_n[1] = e2.y;
        }

        // ---- MFMA: acc = h_prev @ (Uhi,Ulo), 4 indep chains of 8 ----
        f32x4 acc[NSUB][2];
        #pragma unroll
        for (int sub = 0; sub < NSUB; ++sub) {
            acc[sub][0] = (f32x4){0.f, 0.f, 0.f, 0.f};
            acc[sub][1] = (f32x4){0.f, 0.f, 0.f, 0.f};
        }
        if (!first) {
            #pragma unroll
            for (int kt = 0; kt < 8; ++kt) {
                const f16x8 av = *(const f16x8*)&hF[p][n][kt * 32 + quad * 8];
                #pragma unroll
                for (int sub = 0; sub < NSUB; ++sub) {
                    acc[sub][0] = __builtin_amdgcn_mfma_f32_16x16x32_f16(av, Uhi[sub][kt], acc[sub][0], 0, 0, 0);
                    acc[sub][1] = __builtin_amdgcn_mfma_f32_16x16x32_f16(av, Ulo[sub][kt], acc[sub][1], 0, 0, 0);
                }
            }
        }

        // ---- gate ----
        float gate[4];
        #pragma unroll
        for (int reg = 0; reg < 4; ++reg) {
            const float ekb = (reg == 0) ? ekv.x : (reg == 1) ? ekv.y
                            : (reg == 2) ? ekv.z : ekv.w;
            float g = ekb;
            if (!first) {
                const float* rg = redG[q ^ 1][quad * 4 + reg];
                const float4 g0 = *(const float4*)rg;
                const float4 g1 = *(const float4*)(rg + 4);
                g += rn[reg] * (g0.x + g0.y + g0.z + g0.w +
                                g1.x + g1.y + g1.z + g1.w);
            }
            gate[reg] = 1.f / (1.f + __expf(-g));
        }

        // ---- update + packed f16 h write + norm/gate-dot partials ----
        const int pw = p ^ 1;
        float pn[4], gd[4];
        #pragma unroll
        for (int reg = 0; reg < 4; ++reg) {
            const int row = quad * 4 + reg;
            float sq = 0.f, dv = 0.f;
            float u2s[2];
            #pragma unroll
            for (int sub = 0; sub < NSUB; ++sub) {
                const float asum = acc[sub][0][reg] + acc[sub][1][reg];
                float ht = rn[reg] * asum + keysVc[reg][sub] + eWc[sub];
                ht = fmaxf(ht, 0.f);
                const float u2 = rn[reg] * upv[reg][sub] + gate[reg] * ht;
                upv[reg][sub] = u2;
                u2s[sub] = u2;
                sq += u2 * u2;
                dv += u2 * e_n[sub];
            }
            const unsigned int packed =
                ((unsigned int)h_bits((_Float16)u2s[1]) << 16) |
                (unsigned int)h_bits((_Float16)u2s[0]);
            *(unsigned int*)&hF[pw][row][col2] = packed;
            pn[reg] = sq;
            gd[reg] = dv;
        }

        // ---- reload step-invariants IN PLACE (last use passed) ----
        if (sn >= 0) {
            const float2 w2 = *(const float2*)&eWp[(size_t)(b * S + sn) * D + col2];
            eWc[0] = w2.x; eWc[1] = w2.y;
            ekv = *(const float4*)(ek + (size_t)(b * S + sn) * K + kh + quad * 4);
        }

        // ---- value-splitting butterfly: 8 shuffles (was 32) ----
        // v ids 0..3 = pn[0..3], 4..7 = gd[0..3]
        {
            float v0 = pn[0], v1 = pn[1], v2 = pn[2], v3 = pn[3];
            float w0 = gd[0], w1 = gd[1], w2 = gd[2], w3 = gd[3];
            {   // xor 1: split value-bit2 on lane bit0
                const bool hi = (n & 1);
                float k0 = hi ? w0 : v0, x0 = hi ? v0 : w0;
                float k1 = hi ? w1 : v1, x1 = hi ? v1 : w1;
                float k2 = hi ? w2 : v2, x2 = hi ? v2 : w2;
                float k3 = hi ? w3 : v3, x3 = hi ? v3 : w3;
                v0 = k0 + __shfl_xor(x0, 1);
                v1 = k1 + __shfl_xor(x1, 1);
                v2 = k2 + __shfl_xor(x2, 1);
                v3 = k3 + __shfl_xor(x3, 1);
            }
            {   // xor 2: split value-bit1 on lane bit1
                const bool hi = (n & 2);
                float k0 = hi ? v2 : v0, x0 = hi ? v0 : v2;
                float k1 = hi ? v3 : v1, x1 = hi ? v1 : v3;
                v0 = k0 + __shfl_xor(x0, 2);
                v1 = k1 + __shfl_xor(x1, 2);
            }
            {   // xor 4: split value-bit0 on lane bit2
                const bool hi = (n & 4);
                float k0 = hi ? v1 : v0, x0 = hi ? v0 : v1;
                v0 = k0 + __shfl_xor(x0, 4);
            }
            v0 += __shfl_xor(v0, 8);   // full 16-lane sum
            // lane n<8 holds value vid = 4*bit0 | 2*bit1 | bit2
            if (n < 8) {
                const int vid = ((n & 1) << 2) | (n & 2) | ((n >> 2) & 1);
                const int row = quad * 4 + (vid & 3);
                float* dst = (vid & 4) ? &redG[q][row][wave]
                                       : &redN[q][row][wave];
                *dst = v0;
            }
        }

        __syncthreads();   // the ONLY barrier (R12: beats raw s_barrier)

        #pragma unroll
        for (int reg = 0; reg < 4; ++reg) {
            const float* rp = redN[q][quad * 4 + reg];
            const float4 r0 = *(const float4*)rp;
            const float4 r1 = *(const float4*)(rp + 4);
            rn[reg] = rsqrtf(fmaxf(r0.x + r0.y + r0.z + r0.w +
                                   r1.x + r1.y + r1.z + r1.w, 1e-12f));
        }
        p ^= 1; q ^= 1; first = false;
    }

    #pragma unroll
    for (int reg = 0; reg < 4; ++reg) {
        const size_t base = (size_t)(b * K + kh + quad * 4 + reg) * D;
        const float2 o2 = make_float2(rn[reg] * upv[reg][0],
                                      rn[reg] * upv[reg][1]);
        *(float2*)&out[base + col2] = o2;
    }
}

extern "C" void kernel_launch(void* const* d_in, const int* in_sizes, int n_in,
                              void* d_out, int out_size, void* d_ws, size_t ws_size,
                              hipStream_t stream) {
    const int*   prgrph = (const int*)d_in[0];
    const void*  pmask  = d_in[1];
    const float* keys   = (const float*)d_in[2];
    const float* E      = (const float*)d_in[3];
    const float* U      = (const float*)d_in[4];
    const float* V      = (const float*)d_in[5];
    const float* W      = (const float*)d_in[6];
    float* out = (float*)d_out;

    float* ws_enc   = (float*)d_ws;                          // B*S*D  (8 MB)
    float* ws_eW    = ws_enc + (size_t)B * S * D;            // B*S*D  (8 MB)
    float* ws_keysV = ws_eW  + (size_t)B * S * D;            // B*K*D  (4 MB)
    float* ws_ek    = ws_keysV + (size_t)B * K * D;          // B*S*K  (1 MB)
    int*   ws_mask  = (int*)(ws_ek + (size_t)B * S * K);     // B*S

    pre_kernel<<<(B * S) / 32 + (B * K) / 32, 256, 0, stream>>>(
        prgrph, E, W, V, keys, pmask, ws_enc, ws_eW, ws_keysV, ws_ek, ws_mask);
    recur_kernel<<<B * (K / KH), 512, 0, stream>>>(
        ws_enc, ws_eW, ws_keysV, ws_ek, U, ws_mask, out);
}